// Round 12
// baseline (300.723 us; speedup 1.0000x reference)
//
#include <hip/hip_runtime.h>
#include <cstdint>
#include <cstddef>

// ---------------------------------------------------------------------------
// RestrictedTransformerEncoderLayer on MI355X (gfx950)  — ROUND 22
// B=2, L=2048, E=1024, H=16, D=64, FF=4096, WIN=128.
// R22: gemm256 ds_read pipelining (issue-early / wait-late). Old loop waited
// lgkmcnt(0) on same-phase reads -> ~120cy LDS latency exposed 4x per K-step.
// New: prologue issues af+bf0(tile0); P0 issues bf1, waits lgkm(4) [af,bf0
// retired, bf1 flying]; P1 issues ag, waits lgkm(8); P2 waits lgkm(0); P3
// (after counted-vmcnt barrier = tile s+1 landed) issues NEXT tile's af'+bf0'
// (no wait; retired at next P0's lgkm(4)). Every MFMA operand now gets a full
// phase to land. VGPR-neutral: af'/bf0' issued where af/bf0 are dead (peak
// live set unchanged ~224). Region-retire ledger verified: each LDS region's
// readers retire >=1 barrier before its overwriting stage.
// Everything else identical to R21 (gemm64 R19-exact, attn R21 staging,
// vec-LN, conv fusion, w2-in-d_out dataflow).
// Workspace (48 MiB):
//   srcb/x1b bf16 [0,        8388608)
//   qkv  bf16     [8388608,  33554432)  dead after attn
//   ctx  bf16     [33554432, 41943040)  dead after out-proj
//   attnb bf16    [8388608,  16777216)  (reuse qkv)  dead after LN1
//   ff1  bf16     [8388608,  41943040)
//   wslot bf16    [41943040, 50331648)  w_in|w_out -> w1 -> FF2-out (serial)
//   d_out scratch: w2 bf16 [0, 8.4MB) until FF2 completes; then f32 output.
// ---------------------------------------------------------------------------

typedef __attribute__((ext_vector_type(8))) short short8;   // 8 x bf16 MFMA frag
typedef __attribute__((ext_vector_type(4))) float f32x4;    // MFMA accumulator

__device__ __forceinline__ float b2f(unsigned short u) {
  union { unsigned int i; float f; } x; x.i = ((unsigned int)u) << 16; return x.f;
}
__device__ __forceinline__ unsigned short f2b(float f) {
  union { float f; unsigned int i; } x; x.f = f;
  unsigned int i = x.i;
  unsigned int r = (i + 0x7FFFu + ((i >> 16) & 1u)) >> 16;  // RNE
  return (unsigned short)r;
}
__device__ __forceinline__ uint4 pack8(float4 f0, float4 f1) {
  uint4 r;
  r.x = (unsigned)f2b(f0.x) | ((unsigned)f2b(f0.y) << 16);
  r.y = (unsigned)f2b(f0.z) | ((unsigned)f2b(f0.w) << 16);
  r.z = (unsigned)f2b(f1.x) | ((unsigned)f2b(f1.y) << 16);
  r.w = (unsigned)f2b(f1.z) | ((unsigned)f2b(f1.w) << 16);
  return r;
}

// async global->LDS, 16B/lane; LDS base wave-uniform, lanes write base+lane*16
__device__ __forceinline__ void gl_lds16(const unsigned short* g, unsigned short* l) {
  __builtin_amdgcn_global_load_lds(
      (const __attribute__((address_space(1))) unsigned int*)g,
      (__attribute__((address_space(3))) unsigned int*)l, 16, 0, 0);
}

// ---------------------------------------------------------------------------
// Fused convert #1: src (4194304) -> srcb; w_in (3145728) + w_out (1048576)
// -> wslot packed [w_in | w_out]. Total 8388608 elems, grid 4096 x 256.
// ---------------------------------------------------------------------------
__global__ __launch_bounds__(256) void conv3_k(
    const float* __restrict__ src, unsigned short* __restrict__ srcb,
    const float* __restrict__ w_in, const float* __restrict__ w_out,
    unsigned short* __restrict__ wslot)
{
  const int i = (blockIdx.x * 256 + threadIdx.x) * 8;
  const float* in;
  unsigned short* out;
  if (i < 4194304)      { in = src + i;                 out = srcb + i; }
  else if (i < 7340032) { in = w_in + (i - 4194304);    out = wslot + (i - 4194304); }
  else                  { in = w_out + (i - 7340032);   out = wslot + (i - 4194304); }
  const float4 f0 = *(const float4*)(in);
  const float4 f1 = *(const float4*)(in + 4);
  *(uint4*)(out) = pack8(f0, f1);
}

// ---------------------------------------------------------------------------
// Fused convert #2: w1 (4194304) -> wslot; w2 (4194304) -> d_out (bf16
// scratch; d_out untouched until FF2 reads it). Grid 4096 x 256.
// ---------------------------------------------------------------------------
__global__ __launch_bounds__(256) void conv2_k(
    const float* __restrict__ w1, unsigned short* __restrict__ o1,
    const float* __restrict__ w2, unsigned short* __restrict__ o2)
{
  const int i = (blockIdx.x * 256 + threadIdx.x) * 8;
  const float* in;
  unsigned short* out;
  if (i < 4194304) { in = w1 + i;             out = o1 + i; }
  else             { in = w2 + (i - 4194304); out = o2 + (i - 4194304); }
  const float4 f0 = *(const float4*)(in);
  const float4 f1 = *(const float4*)(in + 4);
  *(uint4*)(out) = pack8(f0, f1);
}

// ---------------------------------------------------------------------------
// GEMM 256x256 tile, BK=64, 8-phase schedule (4 phases per K-tile), with
// R22 issue-early/wait-late ds_read pipelining (counted lgkmcnt).
// 512 threads = 8 waves (2M x 4N); per-wave 128x64 split as half-rows.
// LDS 128 KB. r-rotation chunk swizzle (conflict-free).
// ---------------------------------------------------------------------------
template<int RELU, int OUT32>
__global__ __launch_bounds__(512, 2) void gemm256(
    const unsigned short* __restrict__ A, const unsigned short* __restrict__ Wb,
    const float* __restrict__ bias, void* __restrict__ out,
    int M, int N, int K)
{
  __shared__ unsigned short As[2][256 * 64];   // 64 KB
  __shared__ unsigned short Bs[2][256 * 64];   // 64 KB

  const int tid = threadIdx.x;
  const int lane = tid & 63, wid = tid >> 6;
  const int wm = wid >> 2, wn = wid & 3;       // wave grid 2M x 4N

  // XCD-aware bijective remap (grids 192 / 256, both % 8 == 0)
  const int gx = gridDim.x;
  const int flat = blockIdx.y * gx + blockIdx.x;
  const int chunk = (gx * gridDim.y) >> 3;
  const int nf = (flat & 7) * chunk + (flat >> 3);
  const int m0 = (nf / gx) * 256, n0 = (nf % gx) * 256;

  // staging precompute: half h1 in {0 (rows 0-127), 1 (rows 128-255)}, i in {0,1}
  int offA[2][2], offB[2][2], ldsO2[2][2];
#pragma unroll
  for (int h1 = 0; h1 < 2; ++h1)
#pragma unroll
    for (int i = 0; i < 2; ++i) {
      const int sl = i * 512 + tid;            // slot within half (0..1023)
      const int r = h1 * 128 + (sl >> 3);
      const int sslot = sl & 7;
      const int c = (sslot + r) & 7;
      offA[h1][i] = (m0 + r) * K + c * 8;
      offB[h1][i] = (n0 + r) * K + c * 8;
      ldsO2[h1][i] = (h1 * 1024 + i * 512 + (tid & ~63)) * 8;
    }

  const int cl = lane & 15;
  const int kg = lane >> 4;

  int aoff[4][2], boff[2][2];
#pragma unroll
  for (int mt = 0; mt < 4; ++mt) {
    const int ar = wm * 64 + mt * 16 + cl;
#pragma unroll
    for (int ks = 0; ks < 2; ++ks)
      aoff[mt][ks] = ar * 64 + (((ks * 4 + kg) - ar) & 7) * 8;
  }
#pragma unroll
  for (int nt = 0; nt < 2; ++nt) {
    const int br = wn * 32 + nt * 16 + cl;
#pragma unroll
    for (int ks = 0; ks < 2; ++ks)
      boff[nt][ks] = br * 64 + (((ks * 4 + kg) - br) & 7) * 8;
  }
  // rows +128 => offset +8192 elems, rotation unchanged (128 & 7 == 0)

  f32x4 acc[8][4];
#pragma unroll
  for (int i = 0; i < 8; ++i)
#pragma unroll
    for (int j = 0; j < 4; ++j) acc[i][j] = (f32x4){0.f, 0.f, 0.f, 0.f};

  const int steps = K >> 6;

#define STAGE256(idx_) do { const int _x = (idx_); if (_x < 4 * steps) {        \
    const int T_ = _x >> 2, j_ = _x & 3, bf_ = T_ & 1; const int ko = T_ << 6;  \
    if (j_ == 0)      { gl_lds16(A  + offA[0][0] + ko, &As[bf_][ldsO2[0][0]]);  \
                        gl_lds16(A  + offA[0][1] + ko, &As[bf_][ldsO2[0][1]]); }\
    else if (j_ == 1) { gl_lds16(Wb + offB[0][0] + ko, &Bs[bf_][ldsO2[0][0]]);  \
                        gl_lds16(Wb + offB[0][1] + ko, &Bs[bf_][ldsO2[0][1]]); }\
    else if (j_ == 2) { gl_lds16(Wb + offB[1][0] + ko, &Bs[bf_][ldsO2[1][0]]);  \
                        gl_lds16(Wb + offB[1][1] + ko, &Bs[bf_][ldsO2[1][1]]); }\
    else              { gl_lds16(A  + offA[1][0] + ko, &As[bf_][ldsO2[1][0]]);  \
                        gl_lds16(A  + offA[1][1] + ko, &As[bf_][ldsO2[1][1]]); }\
  } } while (0)

  STAGE256(0); STAGE256(1); STAGE256(2); STAGE256(3);
  STAGE256(4); STAGE256(5); STAGE256(6);
  asm volatile("s_waitcnt vmcnt(6)" ::: "memory");   // tile0 fully landed
  __builtin_amdgcn_s_barrier();

  // prologue frag issue: tile0's af (A-half0, 8) + bf0 (B-half0, 4)
  short8 af[4][2], bf0[2][2];
#pragma unroll
  for (int mt = 0; mt < 4; ++mt)
#pragma unroll
    for (int ks = 0; ks < 2; ++ks) af[mt][ks] = *(const short8*)&As[0][aoff[mt][ks]];
#pragma unroll
  for (int nt = 0; nt < 2; ++nt)
#pragma unroll
    for (int ks = 0; ks < 2; ++ks) bf0[nt][ks] = *(const short8*)&Bs[0][boff[nt][ks]];

  int cur = 0;
  for (int s = 0; s < steps; ++s) {
    // ---- P0: issue bf1(4); stage A1(s+1); wait lgkm(4) [af,bf0 done,
    //      bf1 flying]; MFMA af x bf0.
    short8 bf1[2][2];
#pragma unroll
    for (int nt = 0; nt < 2; ++nt)
#pragma unroll
      for (int ks = 0; ks < 2; ++ks) bf1[nt][ks] = *(const short8*)&Bs[cur][boff[nt][ks] + 8192];
    STAGE256(4 * s + 7);
    asm volatile("s_waitcnt lgkmcnt(4)" ::: "memory");
    __builtin_amdgcn_s_barrier();
    __builtin_amdgcn_sched_barrier(0);
    __builtin_amdgcn_s_setprio(1);
#pragma unroll
    for (int mt = 0; mt < 4; ++mt)
#pragma unroll
      for (int nt = 0; nt < 2; ++nt)
#pragma unroll
        for (int ks = 0; ks < 2; ++ks)
          acc[mt][nt] = __builtin_amdgcn_mfma_f32_16x16x32_bf16(af[mt][ks], bf0[nt][ks], acc[mt][nt], 0, 0, 0);
    __builtin_amdgcn_s_setprio(0);
    __builtin_amdgcn_s_barrier();

    // ---- P1: issue ag(8); stage A0(s+2) [af readers retired at P0 lgkm(4)];
    //      wait lgkm(8) [bf1 done, ag flying]; MFMA af x bf1.
    short8 ag[4][2];
#pragma unroll
    for (int mt = 0; mt < 4; ++mt)
#pragma unroll
      for (int ks = 0; ks < 2; ++ks) ag[mt][ks] = *(const short8*)&As[cur][aoff[mt][ks] + 8192];
    STAGE256(4 * s + 8);
    asm volatile("s_waitcnt lgkmcnt(8)" ::: "memory");
    __builtin_amdgcn_s_barrier();
    __builtin_amdgcn_sched_barrier(0);
    __builtin_amdgcn_s_setprio(1);
#pragma unroll
    for (int mt = 0; mt < 4; ++mt)
#pragma unroll
      for (int nt = 0; nt < 2; ++nt)
#pragma unroll
        for (int ks = 0; ks < 2; ++ks)
          acc[mt][nt + 2] = __builtin_amdgcn_mfma_f32_16x16x32_bf16(af[mt][ks], bf1[nt][ks], acc[mt][nt + 2], 0, 0, 0);
    __builtin_amdgcn_s_setprio(0);
    __builtin_amdgcn_s_barrier();

    // ---- P2: stage B0(s+2) [bf0 readers retired at P0 lgkm(4)];
    //      wait lgkm(0) [ag done]; MFMA ag x bf0.
    STAGE256(4 * s + 9);
    asm volatile("s_waitcnt lgkmcnt(0)" ::: "memory");
    __builtin_amdgcn_s_barrier();
    __builtin_amdgcn_sched_barrier(0);
    __builtin_amdgcn_s_setprio(1);
#pragma unroll
    for (int mt = 0; mt < 4; ++mt)
#pragma unroll
      for (int nt = 0; nt < 2; ++nt)
#pragma unroll
        for (int ks = 0; ks < 2; ++ks)
          acc[mt + 4][nt] = __builtin_amdgcn_mfma_f32_16x16x32_bf16(ag[mt][ks], bf0[nt][ks], acc[mt + 4][nt], 0, 0, 0);
    __builtin_amdgcn_s_setprio(0);
    __builtin_amdgcn_s_barrier();

    // ---- P3: stage B1(s+2) [bf1 retired P1]; counted vmcnt; barrier
    //      (tile s+1 fully in LDS); PREFETCH next tile's af'+bf0' (12 reads,
    //      retired at next P0's lgkm(4)); MFMA ag x bf1 (reg-only).
    STAGE256(4 * s + 10);
    if (s < steps - 2)       asm volatile("s_waitcnt vmcnt(6)" ::: "memory");
    else if (s == steps - 2) asm volatile("s_waitcnt vmcnt(0)" ::: "memory");
    __builtin_amdgcn_s_barrier();
    if (s + 1 < steps) {
#pragma unroll
      for (int mt = 0; mt < 4; ++mt)
#pragma unroll
        for (int ks = 0; ks < 2; ++ks) af[mt][ks] = *(const short8*)&As[cur ^ 1][aoff[mt][ks]];
#pragma unroll
      for (int nt = 0; nt < 2; ++nt)
#pragma unroll
        for (int ks = 0; ks < 2; ++ks) bf0[nt][ks] = *(const short8*)&Bs[cur ^ 1][boff[nt][ks]];
    }
    __builtin_amdgcn_s_setprio(1);
#pragma unroll
    for (int mt = 0; mt < 4; ++mt)
#pragma unroll
      for (int nt = 0; nt < 2; ++nt)
#pragma unroll
        for (int ks = 0; ks < 2; ++ks)
          acc[mt + 4][nt + 2] = __builtin_amdgcn_mfma_f32_16x16x32_bf16(ag[mt][ks], bf1[nt][ks], acc[mt + 4][nt + 2], 0, 0, 0);
    __builtin_amdgcn_s_setprio(0);
    __builtin_amdgcn_s_barrier();

    cur ^= 1;
  }
#undef STAGE256

  // epilogue: C/D mapping col = cl, row = kg*4 + r  [m89-verified]
#pragma unroll
  for (int nt = 0; nt < 4; ++nt) {
    const int colB = wn * 32 + (nt & 1) * 16 + (nt >> 1) * 128;
    const int col = n0 + colB + cl;
    const float bvs = bias[col];
#pragma unroll
    for (int mt = 0; mt < 8; ++mt) {
      const int rowA = wm * 64 + (mt & 3) * 16 + (mt >> 2) * 128;
#pragma unroll
      for (int r = 0; r < 4; ++r) {
        const int grow = m0 + rowA + kg * 4 + r;
        float v = acc[mt][nt][r] + bvs;
        if (RELU) v = fmaxf(v, 0.f);
        if (OUT32) ((float*)out)[(size_t)grow * N + col] = v;
        else       ((unsigned short*)out)[(size_t)grow * N + col] = f2b(v);
      }
    }
  }
}

// ---------------------------------------------------------------------------
// GEMM 64x128 tile, BK=64 — N=1024 shapes (grid 512 = 2 blocks/CU).
// R12-EXACT (via R19): 3-deep counted-vmcnt pipeline (72 KB LDS), 4 waves,
// TWO barriers per K-step (proven best: FF2 ~48us). XCD-chunked remap.
// ---------------------------------------------------------------------------
template<int OUT32>
__global__ __launch_bounds__(256) void gemm64(
    const unsigned short* __restrict__ A, const unsigned short* __restrict__ Wb,
    const float* __restrict__ bias, void* __restrict__ out,
    int M, int N, int K)
{
  __shared__ unsigned short As[3][64 * 64];    // 24 KB
  __shared__ unsigned short Bs[3][128 * 64];   // 48 KB

  const int tid = threadIdx.x;
  const int lane = tid & 63, wid = tid >> 6;

  const int nwgx = gridDim.x;
  const int flat = blockIdx.y * nwgx + blockIdx.x;
  const int chunk = (nwgx * gridDim.y) >> 3;
  const int nf = (flat & 7) * chunk + (flat >> 3);
  const int m0 = (nf / nwgx) * 64, n0 = (nf % nwgx) * 128;

  const unsigned short* gA[2];
  const unsigned short* gW[4];
  int ldsA[2], ldsB[4];
#pragma unroll
  for (int i = 0; i < 2; ++i) {
    const int sl = wid * 128 + i * 64 + lane;
    const int r = sl >> 3, s = sl & 7, c = (s + r) & 7;
    gA[i] = A + (size_t)(m0 + r) * K + c * 8;
    ldsA[i] = (wid * 128 + i * 64) * 8;
  }
#pragma unroll
  for (int i = 0; i < 4; ++i) {
    const int sl = wid * 256 + i * 64 + lane;
    const int r = sl >> 3, s = sl & 7, c = (s + r) & 7;
    gW[i] = Wb + (size_t)(n0 + r) * K + c * 8;
    ldsB[i] = (wid * 256 + i * 64) * 8;
  }

  const int cl = lane & 15;
  const int kg = lane >> 4;
  int aoff[4][2], boff[2][2];
#pragma unroll
  for (int t = 0; t < 4; ++t) {
    const int ar = t * 16 + cl;
#pragma unroll
    for (int ks = 0; ks < 2; ++ks)
      aoff[t][ks] = ar * 64 + ((ks * 4 + kg - ar) & 7) * 8;
  }
#pragma unroll
  for (int t = 0; t < 2; ++t) {
    const int br = wid * 32 + t * 16 + cl;
#pragma unroll
    for (int ks = 0; ks < 2; ++ks)
      boff[t][ks] = br * 64 + ((ks * 4 + kg - br) & 7) * 8;
  }

  f32x4 acc[4][2];
#pragma unroll
  for (int i = 0; i < 4; ++i)
#pragma unroll
    for (int j = 0; j < 2; ++j) acc[i][j] = (f32x4){0.f, 0.f, 0.f, 0.f};

  const int steps = K >> 6;

  const int pre = steps < 3 ? steps : 3;
  for (int t = 0; t < pre; ++t) {
#pragma unroll
    for (int i = 0; i < 2; ++i) { gl_lds16(gA[i], &As[t][ldsA[i]]); gA[i] += 64; }
#pragma unroll
    for (int i = 0; i < 4; ++i) { gl_lds16(gW[i], &Bs[t][ldsB[i]]); gW[i] += 64; }
  }

  int cur = 0;
  for (int s = 0; s < steps; ++s) {
    const int rem = steps - 1 - s;
    if (rem >= 2)      asm volatile("s_waitcnt vmcnt(12)" ::: "memory");
    else if (rem == 1) asm volatile("s_waitcnt vmcnt(6)" ::: "memory");
    else               asm volatile("s_waitcnt vmcnt(0)" ::: "memory");
    __builtin_amdgcn_s_barrier();

    short8 af[4][2], bf[2][2];
#pragma unroll
    for (int t = 0; t < 4; ++t)
#pragma unroll
      for (int ks = 0; ks < 2; ++ks) af[t][ks] = *(const short8*)&As[cur][aoff[t][ks]];
#pragma unroll
    for (int t = 0; t < 2; ++t)
#pragma unroll
      for (int ks = 0; ks < 2; ++ks) bf[t][ks] = *(const short8*)&Bs[cur][boff[t][ks]];

    asm volatile("s_waitcnt lgkmcnt(0)" ::: "memory");
    __builtin_amdgcn_sched_barrier(0);
    __builtin_amdgcn_s_barrier();

    if (s + 3 < steps) {
#pragma unroll
      for (int i = 0; i < 2; ++i) { gl_lds16(gA[i], &As[cur][ldsA[i]]); gA[i] += 64; }
#pragma unroll
      for (int i = 0; i < 4; ++i) { gl_lds16(gW[i], &Bs[cur][ldsB[i]]); gW[i] += 64; }
    }

#pragma unroll
    for (int mt = 0; mt < 4; ++mt)
#pragma unroll
      for (int nt = 0; nt < 2; ++nt)
#pragma unroll
        for (int ks = 0; ks < 2; ++ks)
          acc[mt][nt] = __builtin_amdgcn_mfma_f32_16x16x32_bf16(af[mt][ks], bf[nt][ks], acc[mt][nt], 0, 0, 0);

    cur = (cur == 2) ? 0 : cur + 1;
  }

#pragma unroll
  for (int nt = 0; nt < 2; ++nt) {
    const int col = n0 + wid * 32 + nt * 16 + cl;
    const float bvs = bias[col];
#pragma unroll
    for (int mt = 0; mt < 4; ++mt) {
#pragma unroll
      for (int r = 0; r < 4; ++r) {
        const int grow = m0 + mt * 16 + kg * 4 + r;
        const float v = acc[mt][nt][r] + bvs;
        if (OUT32) ((float*)out)[(size_t)grow * N + col] = v;
        else       ((unsigned short*)out)[(size_t)grow * N + col] = f2b(v);
      }
    }
  }
}

// ---------------------------------------------------------------------------
// MFMA flash attention — R21 staging (K via DMA + chunk swizzle; V transpose
// with XOR swizzle), unchanged.
// ---------------------------------------------------------------------------
__global__ __launch_bounds__(256) void attn_mfma(
    const unsigned short* __restrict__ qkv, unsigned short* __restrict__ ctx)
{
  __shared__ unsigned short Ks[64 * 64];   // 8 KB, linear + chunk swizzle
  __shared__ unsigned short Vt[64 * 72];   // 9 KB, transposed + XOR swizzle
  __shared__ unsigned short Ps[64 * 72];   // 9 KB

  const int tid = threadIdx.x;
  const int bid = blockIdx.x;
  const int qt = bid & 31, h = (bid >> 5) & 15, b = bid >> 9;
  const int q0 = qt * 64;
  const int wstart = max(0, q0 - 128);
  const int wend = min(2048, q0 + 64 + 128);
  const int ntile = (wend - wstart) >> 6;    // exact (bounds are x64)
  const size_t rowb = (size_t)b * 2048;

  const int lane = tid & 63, wid = tid >> 6;
  const int cl = lane & 15;
  const int kg = lane >> 4;
  const int kq = kg * 8;
  const int rowg = kg;

  // K staging: 512 slots (64 rows x 8 chunks of 16B), 2 slots/thread via DMA
  const unsigned short* gK[2];
  int ldsK[2];
#pragma unroll
  for (int i = 0; i < 2; ++i) {
    const int sl = i * 256 + tid;
    const int r = sl >> 3, s = sl & 7, c = (s + r) & 7;
    gK[i] = qkv + (rowb + wstart + r) * 3072 + h * 64 + 1024 + c * 8;
    ldsK[i] = (i * 256 + (tid & ~63)) * 8;   // wave-uniform base
  }
  // V loads for transpose: idx = i*256+tid -> row vr, chunk vc
  const unsigned short* gV[2];
  int vr[2], vc[2];
#pragma unroll
  for (int i = 0; i < 2; ++i) {
    const int idx = i * 256 + tid;
    vr[i] = idx >> 3; vc[i] = idx & 7;
    gV[i] = qkv + (rowb + wstart + vr[i]) * 3072 + h * 64 + 2048 + vc[i] * 8;
  }

  // fragment read offsets
  int koff[4][2], voff[4][2];
#pragma unroll
  for (int nt = 0; nt < 4; ++nt) {
    const int jr = nt * 16 + cl;             // K row (S column)
#pragma unroll
    for (int ks = 0; ks < 2; ++ks) {
      koff[nt][ks] = jr * 64 + (((ks * 4 + kg) - jr) & 7) * 8;
      voff[nt][ks] = jr * 72 + ((ks * 32 + kq) ^ (((jr >> 3) & 7) << 3));
    }
  }

  short8 aQ[2];
#pragma unroll
  for (int ks = 0; ks < 2; ++ks)
    aQ[ks] = *(const short8*)(qkv + (rowb + q0 + wid * 16 + cl) * 3072 + h * 64 + ks * 32 + kq);

  float m_i[4], l_i[4];
  f32x4 O[4];
#pragma unroll
  for (int r = 0; r < 4; ++r) { m_i[r] = -1.0e30f; l_i[r] = 0.f; }
#pragma unroll
  for (int nt = 0; nt < 4; ++nt) O[nt] = (f32x4){0.f, 0.f, 0.f, 0.f};

  for (int t = 0; t < ntile; ++t) {
    const int jbase = wstart + t * 64;
    __syncthreads();                          // prev-tile readers done
    gl_lds16(gK[0], &Ks[ldsK[0]]);
    gl_lds16(gK[1], &Ks[ldsK[1]]);
    gK[0] += 196608; gK[1] += 196608;         // advance 64 rows
    const uint4 v0 = *(const uint4*)gV[0];
    const uint4 v1 = *(const uint4*)gV[1];
    gV[0] += 196608; gV[1] += 196608;
    {
      const unsigned short* p = (const unsigned short*)&v0;
      const int col = vr[0] ^ (vc[0] << 3);
#pragma unroll
      for (int ii = 0; ii < 8; ++ii) Vt[(vc[0] * 8 + ii) * 72 + col] = p[ii];
    }
    {
      const unsigned short* p = (const unsigned short*)&v1;
      const int col = vr[1] ^ (vc[1] << 3);
#pragma unroll
      for (int ii = 0; ii < 8; ++ii) Vt[(vc[1] * 8 + ii) * 72 + col] = p[ii];
    }
    __syncthreads();                          // staging visible (full drain)

    f32x4 S[4];
#pragma unroll
    for (int nt = 0; nt < 4; ++nt) S[nt] = (f32x4){0.f, 0.f, 0.f, 0.f};
#pragma unroll
    for (int nt = 0; nt < 4; ++nt)
#pragma unroll
      for (int ks = 0; ks < 2; ++ks) {
        const short8 bK = *(const short8*)&Ks[koff[nt][ks]];
        S[nt] = __builtin_amdgcn_mfma_f32_16x16x32_bf16(aQ[ks], bK, S[nt], 0, 0, 0);
      }

    float sc[4][4];
#pragma unroll
    for (int nt = 0; nt < 4; ++nt) {
      const int jg = jbase + nt * 16 + cl;
#pragma unroll
      for (int r = 0; r < 4; ++r) {
        const int i = q0 + wid * 16 + rowg * 4 + r;
        const bool v = (jg >= i - 128) && (jg <= i + 128);
        sc[nt][r] = v ? S[nt][r] * 0.125f : -1.0e30f;
      }
    }

    float alpha[4], p[4][4];
#pragma unroll
    for (int r = 0; r < 4; ++r) {
      float tm = fmaxf(fmaxf(sc[0][r], sc[1][r]), fmaxf(sc[2][r], sc[3][r]));
      tm = fmaxf(tm, __shfl_xor(tm, 1, 64));
      tm = fmaxf(tm, __shfl_xor(tm, 2, 64));
      tm = fmaxf(tm, __shfl_xor(tm, 4, 64));
      tm = fmaxf(tm, __shfl_xor(tm, 8, 64));
      const float mn = fmaxf(m_i[r], tm);
      alpha[r] = __expf(m_i[r] - mn);
      m_i[r] = mn;
      float ps = 0.f;
#pragma unroll
      for (int nt = 0; nt < 4; ++nt) { p[nt][r] = __expf(sc[nt][r] - mn); ps += p[nt][r]; }
      ps += __shfl_xor(ps, 1, 64);
      ps += __shfl_xor(ps, 2, 64);
      ps += __shfl_xor(ps, 4, 64);
      ps += __shfl_xor(ps, 8, 64);
      l_i[r] = l_i[r] * alpha[r] + ps;
    }

#pragma unroll
    for (int nt = 0; nt < 4; ++nt)
#pragma unroll
      for (int r = 0; r < 4; ++r)
        Ps[(wid * 16 + rowg * 4 + r) * 72 + nt * 16 + cl] = f2b(p[nt][r]);
    __syncthreads();

#pragma unroll
    for (int nt = 0; nt < 4; ++nt)
#pragma unroll
      for (int r = 0; r < 4; ++r) O[nt][r] *= alpha[r];
    short8 aP[2];
#pragma unroll
    for (int ks = 0; ks < 2; ++ks)
      aP[ks] = *(const short8*)&Ps[(wid * 16 + cl) * 72 + ks * 32 + kq];
#pragma unroll
    for (int nt = 0; nt < 4; ++nt)
#pragma unroll
      for (int ks = 0; ks < 2; ++ks) {
        const short8 bV = *(const short8*)&Vt[voff[nt][ks]];
        O[nt] = __builtin_amdgcn_mfma_f32_16x16x32_bf16(aP[ks], bV, O[nt], 0, 0, 0);
      }
  }

#pragma unroll
  for (int nt = 0; nt < 4; ++nt) {
    const int d = nt * 16 + cl;
#pragma unroll
    for (int r = 0; r < 4; ++r) {
      const int i = q0 + wid * 16 + rowg * 4 + r;
      ctx[(rowb + i) * 1024 + h * 64 + d] = f2b(O[nt][r] / l_i[r]);
    }
  }
}

// ---------------------------------------------------------------------------
// Residual + LayerNorm — vectorized (R19). 4 consecutive elems/thread.
// ---------------------------------------------------------------------------
template<int AF32, int BF32, int OF32>
__global__ __launch_bounds__(256) void ln_k(
    const void* __restrict__ a, const void* __restrict__ b,
    const float* __restrict__ g, const float* __restrict__ be,
    void* __restrict__ o)
{
  __shared__ float rbuf[8];
  const int tid = threadIdx.x;
  const size_t base = (size_t)blockIdx.x * 1024;
  const int lane = tid & 63, wid = tid >> 6;
  const int c0 = tid * 4;

  float av[4], bv[4], xv[4];
  if (AF32) {
    const float4 t = *(const float4*)((const float*)a + base + c0);
    av[0] = t.x; av[1] = t.y; av[2] = t.z; av[3] = t.w;
  } else {
    const uint2 t = *(const uint2*)((const unsigned short*)a + base + c0);
    av[0] = b2f((unsigned short)(t.x & 0xffffu)); av[1] = b2f((unsigned short)(t.x >> 16));
    av[2] = b2f((unsigned short)(t.y & 0xffffu)); av[3] = b2f((unsigned short)(t.y >> 16));
  }
  if (BF32) {
    const float4 t = *(const float4*)((const float*)b + base + c0);
    bv[0] = t.x; bv[1] = t.y; bv[2] = t.z; bv[3] = t.w;
  } else {
    const uint2 t = *(const uint2*)((const unsigned short*)b + base + c0);
    bv[0] = b2f((unsigned short)(t.x & 0xffffu)); bv[1] = b2f((unsigned short)(t.x >> 16));
    bv[2] = b2f((unsigned short)(t.y & 0xffffu)); bv[3] = b2f((unsigned short)(t.y >> 16));
  }

  float s = 0.f, sq = 0.f;
#pragma unroll
  for (int t = 0; t < 4; ++t) {
    const float x = av[t] + bv[t];
    xv[t] = x; s += x; sq += x * x;
  }
  for (int o2 = 1; o2 < 64; o2 <<= 1) { s += __shfl_xor(s, o2, 64); sq += __shfl_xor(sq, o2, 64); }
  if (lane == 0) { rbuf[wid] = s; rbuf[wid + 4] = sq; }
  __syncthreads();
  s  = rbuf[0] + rbuf[1] + rbuf[2] + rbuf[3];
  sq = rbuf[4] + rbuf[5] + rbuf[6] + rbuf[7];
  const float mean = s * (1.0f / 1024.f);
  const float var = sq * (1.0f / 1024.f) - mean * mean;
  const float rstd = rsqrtf(var + 1e-5f);

  const float4 gv  = *(const float4*)(g + c0);
  const float4 bev = *(const float4*)(be + c0);
  float y[4];
  y[0] = (xv[0] - mean) * rstd * gv.x + bev.x;
  y[1] = (xv[1] - mean) * rstd * gv.y + bev.y;
  y[2] = (xv[2] - mean) * rstd * gv.z + bev.z;
  y[3] = (xv[3] - mean) * rstd * gv.w + bev.w;

  if (OF32) {
    float4 t; t.x = y[0]; t.y = y[1]; t.z = y[2]; t.w = y[3];
    *(float4*)((float*)o + base + c0) = t;
  } else {
    uint2 t;
    t.x = (unsigned)f2b(y[0]) | ((unsigned)f2b(y[1]) << 16);
    t.y = (unsigned)f2b(y[2]) | ((unsigned)f2b(y[3]) << 16);
    *(uint2*)((unsigned short*)o + base + c0) = t;
  }
}

// ---------------------------------------------------------------------------
extern "C" void kernel_launch(void* const* d_in, const int* in_sizes, int n_in,
                              void* d_out, int out_size, void* d_ws, size_t ws_size,
                              hipStream_t stream)
{
  (void)in_sizes; (void)n_in; (void)out_size; (void)ws_size;
  const float* src   = (const float*)d_in[0];
  const float* w_in  = (const float*)d_in[1];
  const float* b_in  = (const float*)d_in[2];
  const float* w_out = (const float*)d_in[3];
  const float* b_out = (const float*)d_in[4];
  const float* w1    = (const float*)d_in[5];
  const float* b1    = (const float*)d_in[6];
  const float* w2    = (const float*)d_in[7];
  const float* b2    = (const float*)d_in[8];
  const float* g1    = (const float*)d_in[9];
  const float* be1   = (const float*)d_in[10];
  const float* g2    = (const float*)d_in[11];
  const float* be2   = (const float*)d_in[12];

  char* ws = (char*)d_ws;
  unsigned short* srcb  = (unsigned short*)(ws);                 // [0, 8388608)
  unsigned short* x1b   = srcb;                                  // in-place over srcb
  unsigned short* qkv   = (unsigned short*)(ws + 8388608);       // [8388608, 33554432)
  unsigned short* ctx   = (unsigned short*)(ws + 33554432);      // [33554432, 41943040)
  unsigned short* attnb = (unsigned short*)(ws + 8388608);       // reuse qkv head
  unsigned short* ff1   = (unsigned short*)(ws + 8388608);       // [8388608, 41943040)
  unsigned short* wslot = (unsigned short*)(ws + 41943040);      // [41943040, 50331648)
  float*          outf  = (float*)d_out;
  unsigned short* w2b   = (unsigned short*)d_out;                // bf16 scratch until FF2 done

  // 0) fused convert: src -> srcb; w_in|w_out -> wslot (packed)
  conv3_k<<<dim3(4096), 256, 0, stream>>>(src, srcb, w_in, w_out, wslot);
  // 1) QKV projection (gemm256 8-phase pipelined, grid 192) -> bf16 qkv
  gemm256<0, 0><<<dim3(12, 16), 512, 0, stream>>>(srcb, wslot, b_in, qkv, 4096, 3072, 1024);
  // 2) banded MFMA flash attention (R21 staging) -> bf16 ctx
  attn_mfma<<<dim3(1024), 256, 0, stream>>>(qkv, ctx);
  // 3) output projection (gemm64 R19-exact) -> bf16 attnb
  gemm64<0><<<dim3(8, 64), 256, 0, stream>>>(ctx, wslot + 3145728, b_out, attnb, 4096, 1024, 1024);
  // 4) LN1(srcb bf16 + attnb bf16) -> bf16 x1b (in-place over srcb)
  ln_k<0, 0, 0><<<dim3(4096), 256, 0, stream>>>(srcb, attnb, g1, be1, x1b);
  // 5) fused convert: w1 -> wslot; w2 -> d_out (bf16 scratch)
  conv2_k<<<dim3(4096), 256, 0, stream>>>(w1, wslot, w2, w2b);
  // 6) FF1 + ReLU (gemm256 8-phase pipelined, grid 256) -> bf16 ff1
  gemm256<1, 0><<<dim3(16, 16), 512, 0, stream>>>(x1b, wslot, b1, ff1, 4096, 4096, 1024);
  // 7) FF2 (gemm64 R19-exact): A=ff1, W=w2b(d_out), out -> bf16 wslot (w1 dead)
  gemm64<0><<<dim3(8, 64), 256, 0, stream>>>(ff1, w2b, b2, wslot, 4096, 1024, 4096);
  // 8) LN2(x1b bf16 + wslot bf16) -> f32 d_out (w2 scratch fully consumed)
  ln_k<0, 0, 1><<<dim3(4096), 256, 0, stream>>>(x1b, wslot, g2, be2, outf);
}

// Round 13
// 291.045 us; speedup vs baseline: 1.0333x; 1.0333x over previous
//
#include <hip/hip_runtime.h>
#include <cstdint>
#include <cstddef>

// ---------------------------------------------------------------------------
// RestrictedTransformerEncoderLayer on MI355X (gfx950)  — ROUND 23
// B=2, L=2048, E=1024, H=16, D=64, FF=4096, WIN=128.
// R23: (1) gemm256 reverted to R21/R17-exact — R22's issue-early/wait-late
// frag pipelining was 295.8->300.7 (TLP already hid ds_read latency; hand
// waits only constrained the scheduler). (2) ALL weight/src conversion in
// ONE launch (conv4_k): src->srcb, w_in|w_out->wslot, w1->d_out[8.4M,16.7M),
// w2->d_out[0,8.4M). d_out is untouched until FF2 reads both halves; LN2
// overwrites d_out only after. 9 -> 8 launches (~5us/gap serial chain).
// Everything else identical to R21 (gemm64 R19-exact, attn R21 staging,
// vec-LN).
// Workspace (48 MiB):
//   srcb/x1b bf16 [0,        8388608)
//   qkv  bf16     [8388608,  33554432)  dead after attn
//   ctx  bf16     [33554432, 41943040)  dead after out-proj
//   attnb bf16    [8388608,  16777216)  (reuse qkv)  dead after LN1
//   ff1  bf16     [8388608,  41943040)
//   wslot bf16    [41943040, 50331648)  w_in|w_out -> FF2-out (serial)
//   d_out scratch (16.7MB): w2b [0,8.4M) + w1b [8.4M,16.7M) until FF2 done;
//   then f32 output (LN2).
// ---------------------------------------------------------------------------

typedef __attribute__((ext_vector_type(8))) short short8;   // 8 x bf16 MFMA frag
typedef __attribute__((ext_vector_type(4))) float f32x4;    // MFMA accumulator

__device__ __forceinline__ float b2f(unsigned short u) {
  union { unsigned int i; float f; } x; x.i = ((unsigned int)u) << 16; return x.f;
}
__device__ __forceinline__ unsigned short f2b(float f) {
  union { float f; unsigned int i; } x; x.f = f;
  unsigned int i = x.i;
  unsigned int r = (i + 0x7FFFu + ((i >> 16) & 1u)) >> 16;  // RNE
  return (unsigned short)r;
}
__device__ __forceinline__ uint4 pack8(float4 f0, float4 f1) {
  uint4 r;
  r.x = (unsigned)f2b(f0.x) | ((unsigned)f2b(f0.y) << 16);
  r.y = (unsigned)f2b(f0.z) | ((unsigned)f2b(f0.w) << 16);
  r.z = (unsigned)f2b(f1.x) | ((unsigned)f2b(f1.y) << 16);
  r.w = (unsigned)f2b(f1.z) | ((unsigned)f2b(f1.w) << 16);
  return r;
}

// async global->LDS, 16B/lane; LDS base wave-uniform, lanes write base+lane*16
__device__ __forceinline__ void gl_lds16(const unsigned short* g, unsigned short* l) {
  __builtin_amdgcn_global_load_lds(
      (const __attribute__((address_space(1))) unsigned int*)g,
      (__attribute__((address_space(3))) unsigned int*)l, 16, 0, 0);
}

// ---------------------------------------------------------------------------
// Fused convert (ALL): src (4194304) -> srcb; w_in (3145728)+w_out (1048576)
// -> wslot packed; w1 (4194304) -> w1b; w2 (4194304) -> w2b.
// Total 16777216 elems, grid 8192 x 256. All boundaries multiples of 8.
// ---------------------------------------------------------------------------
__global__ __launch_bounds__(256) void conv4_k(
    const float* __restrict__ src, unsigned short* __restrict__ srcb,
    const float* __restrict__ w_in, const float* __restrict__ w_out,
    unsigned short* __restrict__ wslot,
    const float* __restrict__ w1, unsigned short* __restrict__ w1b,
    const float* __restrict__ w2, unsigned short* __restrict__ w2b)
{
  const int i = (blockIdx.x * 256 + threadIdx.x) * 8;
  const float* in;
  unsigned short* out;
  if (i < 4194304)       { in = src + i;                  out = srcb + i; }
  else if (i < 7340032)  { in = w_in + (i - 4194304);     out = wslot + (i - 4194304); }
  else if (i < 8388608)  { in = w_out + (i - 7340032);    out = wslot + (i - 4194304); }
  else if (i < 12582912) { in = w1 + (i - 8388608);       out = w1b + (i - 8388608); }
  else                   { in = w2 + (i - 12582912);      out = w2b + (i - 12582912); }
  const float4 f0 = *(const float4*)(in);
  const float4 f1 = *(const float4*)(in + 4);
  *(uint4*)(out) = pack8(f0, f1);
}

// ---------------------------------------------------------------------------
// GEMM 256x256 tile, BK=64, 8-phase schedule (4 phases per K-tile).
// 512 threads = 8 waves (2M x 4N); per-wave 128x64 split as half-rows.
// LDS 128 KB. r-rotation chunk swizzle (conflict-free). [R17/R21-exact]
// ---------------------------------------------------------------------------
template<int RELU, int OUT32>
__global__ __launch_bounds__(512, 2) void gemm256(
    const unsigned short* __restrict__ A, const unsigned short* __restrict__ Wb,
    const float* __restrict__ bias, void* __restrict__ out,
    int M, int N, int K)
{
  __shared__ unsigned short As[2][256 * 64];   // 64 KB
  __shared__ unsigned short Bs[2][256 * 64];   // 64 KB

  const int tid = threadIdx.x;
  const int lane = tid & 63, wid = tid >> 6;
  const int wm = wid >> 2, wn = wid & 3;       // wave grid 2M x 4N

  // XCD-aware bijective remap (grids 192 / 256, both % 8 == 0)
  const int gx = gridDim.x;
  const int flat = blockIdx.y * gx + blockIdx.x;
  const int chunk = (gx * gridDim.y) >> 3;
  const int nf = (flat & 7) * chunk + (flat >> 3);
  const int m0 = (nf / gx) * 256, n0 = (nf % gx) * 256;

  // staging precompute: half h1 in {0 (rows 0-127), 1 (rows 128-255)}, i in {0,1}
  int offA[2][2], offB[2][2], ldsO2[2][2];
#pragma unroll
  for (int h1 = 0; h1 < 2; ++h1)
#pragma unroll
    for (int i = 0; i < 2; ++i) {
      const int sl = i * 512 + tid;            // slot within half (0..1023)
      const int r = h1 * 128 + (sl >> 3);
      const int sslot = sl & 7;
      const int c = (sslot + r) & 7;
      offA[h1][i] = (m0 + r) * K + c * 8;
      offB[h1][i] = (n0 + r) * K + c * 8;
      ldsO2[h1][i] = (h1 * 1024 + i * 512 + (tid & ~63)) * 8;
    }

  const int cl = lane & 15;
  const int kg = lane >> 4;

  int aoff[4][2], boff[2][2];
#pragma unroll
  for (int mt = 0; mt < 4; ++mt) {
    const int ar = wm * 64 + mt * 16 + cl;
#pragma unroll
    for (int ks = 0; ks < 2; ++ks)
      aoff[mt][ks] = ar * 64 + (((ks * 4 + kg) - ar) & 7) * 8;
  }
#pragma unroll
  for (int nt = 0; nt < 2; ++nt) {
    const int br = wn * 32 + nt * 16 + cl;
#pragma unroll
    for (int ks = 0; ks < 2; ++ks)
      boff[nt][ks] = br * 64 + (((ks * 4 + kg) - br) & 7) * 8;
  }
  // rows +128 => offset +8192 elems, rotation unchanged (128 & 7 == 0)

  f32x4 acc[8][4];
#pragma unroll
  for (int i = 0; i < 8; ++i)
#pragma unroll
    for (int j = 0; j < 4; ++j) acc[i][j] = (f32x4){0.f, 0.f, 0.f, 0.f};

  const int steps = K >> 6;

#define STAGE256(idx_) do { const int _x = (idx_); if (_x < 4 * steps) {        \
    const int T_ = _x >> 2, j_ = _x & 3, bf_ = T_ & 1; const int ko = T_ << 6;  \
    if (j_ == 0)      { gl_lds16(A  + offA[0][0] + ko, &As[bf_][ldsO2[0][0]]);  \
                        gl_lds16(A  + offA[0][1] + ko, &As[bf_][ldsO2[0][1]]); }\
    else if (j_ == 1) { gl_lds16(Wb + offB[0][0] + ko, &Bs[bf_][ldsO2[0][0]]);  \
                        gl_lds16(Wb + offB[0][1] + ko, &Bs[bf_][ldsO2[0][1]]); }\
    else if (j_ == 2) { gl_lds16(Wb + offB[1][0] + ko, &Bs[bf_][ldsO2[1][0]]);  \
                        gl_lds16(Wb + offB[1][1] + ko, &Bs[bf_][ldsO2[1][1]]); }\
    else              { gl_lds16(A  + offA[1][0] + ko, &As[bf_][ldsO2[1][0]]);  \
                        gl_lds16(A  + offA[1][1] + ko, &As[bf_][ldsO2[1][1]]); }\
  } } while (0)

  STAGE256(0); STAGE256(1); STAGE256(2); STAGE256(3);
  STAGE256(4); STAGE256(5); STAGE256(6);
  asm volatile("s_waitcnt vmcnt(6)" ::: "memory");   // tile0 fully landed
  __builtin_amdgcn_s_barrier();

  int cur = 0;
  for (int s = 0; s < steps; ++s) {
    // ---- P0: read B-half0 + A-half0; stage tile s+1's A1
    short8 bf0[2][2], af[4][2];
#pragma unroll
    for (int nt = 0; nt < 2; ++nt)
#pragma unroll
      for (int ks = 0; ks < 2; ++ks) bf0[nt][ks] = *(const short8*)&Bs[cur][boff[nt][ks]];
#pragma unroll
    for (int mt = 0; mt < 4; ++mt)
#pragma unroll
      for (int ks = 0; ks < 2; ++ks) af[mt][ks] = *(const short8*)&As[cur][aoff[mt][ks]];
    STAGE256(4 * s + 7);
    asm volatile("s_waitcnt lgkmcnt(8)" ::: "memory");
    __builtin_amdgcn_s_barrier();
    asm volatile("s_waitcnt lgkmcnt(0)" ::: "memory");
    __builtin_amdgcn_sched_barrier(0);
    __builtin_amdgcn_s_setprio(1);
#pragma unroll
    for (int mt = 0; mt < 4; ++mt)
#pragma unroll
      for (int nt = 0; nt < 2; ++nt)
#pragma unroll
        for (int ks = 0; ks < 2; ++ks)
          acc[mt][nt] = __builtin_amdgcn_mfma_f32_16x16x32_bf16(af[mt][ks], bf0[nt][ks], acc[mt][nt], 0, 0, 0);
    __builtin_amdgcn_s_setprio(0);
    __builtin_amdgcn_s_barrier();

    // ---- P1: read B-half1; stage tile s+2's A0 (dead since P0)
    short8 bf1[2][2];
#pragma unroll
    for (int nt = 0; nt < 2; ++nt)
#pragma unroll
      for (int ks = 0; ks < 2; ++ks) bf1[nt][ks] = *(const short8*)&Bs[cur][boff[nt][ks] + 8192];
    STAGE256(4 * s + 8);
    __builtin_amdgcn_s_barrier();
    asm volatile("s_waitcnt lgkmcnt(0)" ::: "memory");
    __builtin_amdgcn_sched_barrier(0);
    __builtin_amdgcn_s_setprio(1);
#pragma unroll
    for (int mt = 0; mt < 4; ++mt)
#pragma unroll
      for (int nt = 0; nt < 2; ++nt)
#pragma unroll
        for (int ks = 0; ks < 2; ++ks)
          acc[mt][nt + 2] = __builtin_amdgcn_mfma_f32_16x16x32_bf16(af[mt][ks], bf1[nt][ks], acc[mt][nt + 2], 0, 0, 0);
    __builtin_amdgcn_s_setprio(0);
    __builtin_amdgcn_s_barrier();

    // ---- P2: read A-half1; stage tile s+2's B0 (dead since P0)
    short8 ag[4][2];
#pragma unroll
    for (int mt = 0; mt < 4; ++mt)
#pragma unroll
      for (int ks = 0; ks < 2; ++ks) ag[mt][ks] = *(const short8*)&As[cur][aoff[mt][ks] + 8192];
    STAGE256(4 * s + 9);
    __builtin_amdgcn_s_barrier();
    asm volatile("s_waitcnt lgkmcnt(0)" ::: "memory");
    __builtin_amdgcn_sched_barrier(0);
    __builtin_amdgcn_s_setprio(1);
#pragma unroll
    for (int mt = 0; mt < 4; ++mt)
#pragma unroll
      for (int nt = 0; nt < 2; ++nt)
#pragma unroll
        for (int ks = 0; ks < 2; ++ks)
          acc[mt + 4][nt] = __builtin_amdgcn_mfma_f32_16x16x32_bf16(ag[mt][ks], bf0[nt][ks], acc[mt + 4][nt], 0, 0, 0);
    __builtin_amdgcn_s_setprio(0);
    __builtin_amdgcn_s_barrier();

    // ---- P3: stage tile s+2's B1 (dead since P1); counted vmcnt; MFMA
    STAGE256(4 * s + 10);
    if (s < steps - 2)       asm volatile("s_waitcnt vmcnt(6)" ::: "memory");
    else if (s == steps - 2) asm volatile("s_waitcnt vmcnt(0)" ::: "memory");
    __builtin_amdgcn_s_barrier();   // tile s+1 now fully visible
    __builtin_amdgcn_s_setprio(1);
#pragma unroll
    for (int mt = 0; mt < 4; ++mt)
#pragma unroll
      for (int nt = 0; nt < 2; ++nt)
#pragma unroll
        for (int ks = 0; ks < 2; ++ks)
          acc[mt + 4][nt + 2] = __builtin_amdgcn_mfma_f32_16x16x32_bf16(ag[mt][ks], bf1[nt][ks], acc[mt + 4][nt + 2], 0, 0, 0);
    __builtin_amdgcn_s_setprio(0);
    __builtin_amdgcn_s_barrier();

    cur ^= 1;
  }
#undef STAGE256

  // epilogue: C/D mapping col = cl, row = kg*4 + r  [m89-verified]
#pragma unroll
  for (int nt = 0; nt < 4; ++nt) {
    const int colB = wn * 32 + (nt & 1) * 16 + (nt >> 1) * 128;
    const int col = n0 + colB + cl;
    const float bvs = bias[col];
#pragma unroll
    for (int mt = 0; mt < 8; ++mt) {
      const int rowA = wm * 64 + (mt & 3) * 16 + (mt >> 2) * 128;
#pragma unroll
      for (int r = 0; r < 4; ++r) {
        const int grow = m0 + rowA + kg * 4 + r;
        float v = acc[mt][nt][r] + bvs;
        if (RELU) v = fmaxf(v, 0.f);
        if (OUT32) ((float*)out)[(size_t)grow * N + col] = v;
        else       ((unsigned short*)out)[(size_t)grow * N + col] = f2b(v);
      }
    }
  }
}

// ---------------------------------------------------------------------------
// GEMM 64x128 tile, BK=64 — N=1024 shapes (grid 512 = 2 blocks/CU).
// R12-EXACT (via R19): 3-deep counted-vmcnt pipeline (72 KB LDS), 4 waves,
// TWO barriers per K-step (proven best: FF2 ~48us). XCD-chunked remap.
// ---------------------------------------------------------------------------
template<int OUT32>
__global__ __launch_bounds__(256) void gemm64(
    const unsigned short* __restrict__ A, const unsigned short* __restrict__ Wb,
    const float* __restrict__ bias, void* __restrict__ out,
    int M, int N, int K)
{
  __shared__ unsigned short As[3][64 * 64];    // 24 KB
  __shared__ unsigned short Bs[3][128 * 64];   // 48 KB

  const int tid = threadIdx.x;
  const int lane = tid & 63, wid = tid >> 6;

  const int nwgx = gridDim.x;
  const int flat = blockIdx.y * nwgx + blockIdx.x;
  const int chunk = (nwgx * gridDim.y) >> 3;
  const int nf = (flat & 7) * chunk + (flat >> 3);
  const int m0 = (nf / nwgx) * 64, n0 = (nf % nwgx) * 128;

  const unsigned short* gA[2];
  const unsigned short* gW[4];
  int ldsA[2], ldsB[4];
#pragma unroll
  for (int i = 0; i < 2; ++i) {
    const int sl = wid * 128 + i * 64 + lane;
    const int r = sl >> 3, s = sl & 7, c = (s + r) & 7;
    gA[i] = A + (size_t)(m0 + r) * K + c * 8;
    ldsA[i] = (wid * 128 + i * 64) * 8;
  }
#pragma unroll
  for (int i = 0; i < 4; ++i) {
    const int sl = wid * 256 + i * 64 + lane;
    const int r = sl >> 3, s = sl & 7, c = (s + r) & 7;
    gW[i] = Wb + (size_t)(n0 + r) * K + c * 8;
    ldsB[i] = (wid * 256 + i * 64) * 8;
  }

  const int cl = lane & 15;
  const int kg = lane >> 4;
  int aoff[4][2], boff[2][2];
#pragma unroll
  for (int t = 0; t < 4; ++t) {
    const int ar = t * 16 + cl;
#pragma unroll
    for (int ks = 0; ks < 2; ++ks)
      aoff[t][ks] = ar * 64 + ((ks * 4 + kg - ar) & 7) * 8;
  }
#pragma unroll
  for (int t = 0; t < 2; ++t) {
    const int br = wid * 32 + t * 16 + cl;
#pragma unroll
    for (int ks = 0; ks < 2; ++ks)
      boff[t][ks] = br * 64 + ((ks * 4 + kg - br) & 7) * 8;
  }

  f32x4 acc[4][2];
#pragma unroll
  for (int i = 0; i < 4; ++i)
#pragma unroll
    for (int j = 0; j < 2; ++j) acc[i][j] = (f32x4){0.f, 0.f, 0.f, 0.f};

  const int steps = K >> 6;

  const int pre = steps < 3 ? steps : 3;
  for (int t = 0; t < pre; ++t) {
#pragma unroll
    for (int i = 0; i < 2; ++i) { gl_lds16(gA[i], &As[t][ldsA[i]]); gA[i] += 64; }
#pragma unroll
    for (int i = 0; i < 4; ++i) { gl_lds16(gW[i], &Bs[t][ldsB[i]]); gW[i] += 64; }
  }

  int cur = 0;
  for (int s = 0; s < steps; ++s) {
    const int rem = steps - 1 - s;
    if (rem >= 2)      asm volatile("s_waitcnt vmcnt(12)" ::: "memory");
    else if (rem == 1) asm volatile("s_waitcnt vmcnt(6)" ::: "memory");
    else               asm volatile("s_waitcnt vmcnt(0)" ::: "memory");
    __builtin_amdgcn_s_barrier();

    short8 af[4][2], bf[2][2];
#pragma unroll
    for (int t = 0; t < 4; ++t)
#pragma unroll
      for (int ks = 0; ks < 2; ++ks) af[t][ks] = *(const short8*)&As[cur][aoff[t][ks]];
#pragma unroll
    for (int t = 0; t < 2; ++t)
#pragma unroll
      for (int ks = 0; ks < 2; ++ks) bf[t][ks] = *(const short8*)&Bs[cur][boff[t][ks]];

    asm volatile("s_waitcnt lgkmcnt(0)" ::: "memory");
    __builtin_amdgcn_sched_barrier(0);
    __builtin_amdgcn_s_barrier();

    if (s + 3 < steps) {
#pragma unroll
      for (int i = 0; i < 2; ++i) { gl_lds16(gA[i], &As[cur][ldsA[i]]); gA[i] += 64; }
#pragma unroll
      for (int i = 0; i < 4; ++i) { gl_lds16(gW[i], &Bs[cur][ldsB[i]]); gW[i] += 64; }
    }

#pragma unroll
    for (int mt = 0; mt < 4; ++mt)
#pragma unroll
      for (int nt = 0; nt < 2; ++nt)
#pragma unroll
        for (int ks = 0; ks < 2; ++ks)
          acc[mt][nt] = __builtin_amdgcn_mfma_f32_16x16x32_bf16(af[mt][ks], bf[nt][ks], acc[mt][nt], 0, 0, 0);

    cur = (cur == 2) ? 0 : cur + 1;
  }

#pragma unroll
  for (int nt = 0; nt < 2; ++nt) {
    const int col = n0 + wid * 32 + nt * 16 + cl;
    const float bvs = bias[col];
#pragma unroll
    for (int mt = 0; mt < 4; ++mt) {
#pragma unroll
      for (int r = 0; r < 4; ++r) {
        const int grow = m0 + mt * 16 + kg * 4 + r;
        const float v = acc[mt][nt][r] + bvs;
        if (OUT32) ((float*)out)[(size_t)grow * N + col] = v;
        else       ((unsigned short*)out)[(size_t)grow * N + col] = f2b(v);
      }
    }
  }
}

// ---------------------------------------------------------------------------
// MFMA flash attention — R21 staging (K via DMA + chunk swizzle; V transpose
// with XOR swizzle), unchanged.
// ---------------------------------------------------------------------------
__global__ __launch_bounds__(256) void attn_mfma(
    const unsigned short* __restrict__ qkv, unsigned short* __restrict__ ctx)
{
  __shared__ unsigned short Ks[64 * 64];   // 8 KB, linear + chunk swizzle
  __shared__ unsigned short Vt[64 * 72];   // 9 KB, transposed + XOR swizzle
  __shared__ unsigned short Ps[64 * 72];   // 9 KB

  const int tid = threadIdx.x;
  const int bid = blockIdx.x;
  const int qt = bid & 31, h = (bid >> 5) & 15, b = bid >> 9;
  const int q0 = qt * 64;
  const int wstart = max(0, q0 - 128);
  const int wend = min(2048, q0 + 64 + 128);
  const int ntile = (wend - wstart) >> 6;    // exact (bounds are x64)
  const size_t rowb = (size_t)b * 2048;

  const int lane = tid & 63, wid = tid >> 6;
  const int cl = lane & 15;
  const int kg = lane >> 4;
  const int kq = kg * 8;
  const int rowg = kg;

  // K staging: 512 slots (64 rows x 8 chunks of 16B), 2 slots/thread via DMA
  const unsigned short* gK[2];
  int ldsK[2];
#pragma unroll
  for (int i = 0; i < 2; ++i) {
    const int sl = i * 256 + tid;
    const int r = sl >> 3, s = sl & 7, c = (s + r) & 7;
    gK[i] = qkv + (rowb + wstart + r) * 3072 + h * 64 + 1024 + c * 8;
    ldsK[i] = (i * 256 + (tid & ~63)) * 8;   // wave-uniform base
  }
  // V loads for transpose: idx = i*256+tid -> row vr, chunk vc
  const unsigned short* gV[2];
  int vr[2], vc[2];
#pragma unroll
  for (int i = 0; i < 2; ++i) {
    const int idx = i * 256 + tid;
    vr[i] = idx >> 3; vc[i] = idx & 7;
    gV[i] = qkv + (rowb + wstart + vr[i]) * 3072 + h * 64 + 2048 + vc[i] * 8;
  }

  // fragment read offsets
  int koff[4][2], voff[4][2];
#pragma unroll
  for (int nt = 0; nt < 4; ++nt) {
    const int jr = nt * 16 + cl;             // K row (S column)
#pragma unroll
    for (int ks = 0; ks < 2; ++ks) {
      koff[nt][ks] = jr * 64 + (((ks * 4 + kg) - jr) & 7) * 8;
      voff[nt][ks] = jr * 72 + ((ks * 32 + kq) ^ (((jr >> 3) & 7) << 3));
    }
  }

  short8 aQ[2];
#pragma unroll
  for (int ks = 0; ks < 2; ++ks)
    aQ[ks] = *(const short8*)(qkv + (rowb + q0 + wid * 16 + cl) * 3072 + h * 64 + ks * 32 + kq);

  float m_i[4], l_i[4];
  f32x4 O[4];
#pragma unroll
  for (int r = 0; r < 4; ++r) { m_i[r] = -1.0e30f; l_i[r] = 0.f; }
#pragma unroll
  for (int nt = 0; nt < 4; ++nt) O[nt] = (f32x4){0.f, 0.f, 0.f, 0.f};

  for (int t = 0; t < ntile; ++t) {
    const int jbase = wstart + t * 64;
    __syncthreads();                          // prev-tile readers done
    gl_lds16(gK[0], &Ks[ldsK[0]]);
    gl_lds16(gK[1], &Ks[ldsK[1]]);
    gK[0] += 196608; gK[1] += 196608;         // advance 64 rows
    const uint4 v0 = *(const uint4*)gV[0];
    const uint4 v1 = *(const uint4*)gV[1];
    gV[0] += 196608; gV[1] += 196608;
    {
      const unsigned short* p = (const unsigned short*)&v0;
      const int col = vr[0] ^ (vc[0] << 3);
#pragma unroll
      for (int ii = 0; ii < 8; ++ii) Vt[(vc[0] * 8 + ii) * 72 + col] = p[ii];
    }
    {
      const unsigned short* p = (const unsigned short*)&v1;
      const int col = vr[1] ^ (vc[1] << 3);
#pragma unroll
      for (int ii = 0; ii < 8; ++ii) Vt[(vc[1] * 8 + ii) * 72 + col] = p[ii];
    }
    __syncthreads();                          // staging visible (full drain)

    f32x4 S[4];
#pragma unroll
    for (int nt = 0; nt < 4; ++nt) S[nt] = (f32x4){0.f, 0.f, 0.f, 0.f};
#pragma unroll
    for (int nt = 0; nt < 4; ++nt)
#pragma unroll
      for (int ks = 0; ks < 2; ++ks) {
        const short8 bK = *(const short8*)&Ks[koff[nt][ks]];
        S[nt] = __builtin_amdgcn_mfma_f32_16x16x32_bf16(aQ[ks], bK, S[nt], 0, 0, 0);
      }

    float sc[4][4];
#pragma unroll
    for (int nt = 0; nt < 4; ++nt) {
      const int jg = jbase + nt * 16 + cl;
#pragma unroll
      for (int r = 0; r < 4; ++r) {
        const int i = q0 + wid * 16 + rowg * 4 + r;
        const bool v = (jg >= i - 128) && (jg <= i + 128);
        sc[nt][r] = v ? S[nt][r] * 0.125f : -1.0e30f;
      }
    }

    float alpha[4], p[4][4];
#pragma unroll
    for (int r = 0; r < 4; ++r) {
      float tm = fmaxf(fmaxf(sc[0][r], sc[1][r]), fmaxf(sc[2][r], sc[3][r]));
      tm = fmaxf(tm, __shfl_xor(tm, 1, 64));
      tm = fmaxf(tm, __shfl_xor(tm, 2, 64));
      tm = fmaxf(tm, __shfl_xor(tm, 4, 64));
      tm = fmaxf(tm, __shfl_xor(tm, 8, 64));
      const float mn = fmaxf(m_i[r], tm);
      alpha[r] = __expf(m_i[r] - mn);
      m_i[r] = mn;
      float ps = 0.f;
#pragma unroll
      for (int nt = 0; nt < 4; ++nt) { p[nt][r] = __expf(sc[nt][r] - mn); ps += p[nt][r]; }
      ps += __shfl_xor(ps, 1, 64);
      ps += __shfl_xor(ps, 2, 64);
      ps += __shfl_xor(ps, 4, 64);
      ps += __shfl_xor(ps, 8, 64);
      l_i[r] = l_i[r] * alpha[r] + ps;
    }

#pragma unroll
    for (int nt = 0; nt < 4; ++nt)
#pragma unroll
      for (int r = 0; r < 4; ++r)
        Ps[(wid * 16 + rowg * 4 + r) * 72 + nt * 16 + cl] = f2b(p[nt][r]);
    __syncthreads();

#pragma unroll
    for (int nt = 0; nt < 4; ++nt)
#pragma unroll
      for (int r = 0; r < 4; ++r) O[nt][r] *= alpha[r];
    short8 aP[2];
#pragma unroll
    for (int ks = 0; ks < 2; ++ks)
      aP[ks] = *(const short8*)&Ps[(wid * 16 + cl) * 72 + ks * 32 + kq];
#pragma unroll
    for (int nt = 0; nt < 4; ++nt)
#pragma unroll
      for (int ks = 0; ks < 2; ++ks) {
        const short8 bV = *(const short8*)&Vt[voff[nt][ks]];
        O[nt] = __builtin_amdgcn_mfma_f32_16x16x32_bf16(aP[ks], bV, O[nt], 0, 0, 0);
      }
  }

#pragma unroll
  for (int nt = 0; nt < 4; ++nt) {
    const int d = nt * 16 + cl;
#pragma unroll
    for (int r = 0; r < 4; ++r) {
      const int i = q0 + wid * 16 + rowg * 4 + r;
      ctx[(rowb + i) * 1024 + h * 64 + d] = f2b(O[nt][r] / l_i[r]);
    }
  }
}

// ---------------------------------------------------------------------------
// Residual + LayerNorm — vectorized (R19). 4 consecutive elems/thread.
// ---------------------------------------------------------------------------
template<int AF32, int BF32, int OF32>
__global__ __launch_bounds__(256) void ln_k(
    const void* __restrict__ a, const void* __restrict__ b,
    const float* __restrict__ g, const float* __restrict__ be,
    void* __restrict__ o)
{
  __shared__ float rbuf[8];
  const int tid = threadIdx.x;
  const size_t base = (size_t)blockIdx.x * 1024;
  const int lane = tid & 63, wid = tid >> 6;
  const int c0 = tid * 4;

  float av[4], bv[4], xv[4];
  if (AF32) {
    const float4 t = *(const float4*)((const float*)a + base + c0);
    av[0] = t.x; av[1] = t.y; av[2] = t.z; av[3] = t.w;
  } else {
    const uint2 t = *(const uint2*)((const unsigned short*)a + base + c0);
    av[0] = b2f((unsigned short)(t.x & 0xffffu)); av[1] = b2f((unsigned short)(t.x >> 16));
    av[2] = b2f((unsigned short)(t.y & 0xffffu)); av[3] = b2f((unsigned short)(t.y >> 16));
  }
  if (BF32) {
    const float4 t = *(const float4*)((const float*)b + base + c0);
    bv[0] = t.x; bv[1] = t.y; bv[2] = t.z; bv[3] = t.w;
  } else {
    const uint2 t = *(const uint2*)((const unsigned short*)b + base + c0);
    bv[0] = b2f((unsigned short)(t.x & 0xffffu)); bv[1] = b2f((unsigned short)(t.x >> 16));
    bv[2] = b2f((unsigned short)(t.y & 0xffffu)); bv[3] = b2f((unsigned short)(t.y >> 16));
  }

  float s = 0.f, sq = 0.f;
#pragma unroll
  for (int t = 0; t < 4; ++t) {
    const float x = av[t] + bv[t];
    xv[t] = x; s += x; sq += x * x;
  }
  for (int o2 = 1; o2 < 64; o2 <<= 1) { s += __shfl_xor(s, o2, 64); sq += __shfl_xor(sq, o2, 64); }
  if (lane == 0) { rbuf[wid] = s; rbuf[wid + 4] = sq; }
  __syncthreads();
  s  = rbuf[0] + rbuf[1] + rbuf[2] + rbuf[3];
  sq = rbuf[4] + rbuf[5] + rbuf[6] + rbuf[7];
  const float mean = s * (1.0f / 1024.f);
  const float var = sq * (1.0f / 1024.f) - mean * mean;
  const float rstd = rsqrtf(var + 1e-5f);

  const float4 gv  = *(const float4*)(g + c0);
  const float4 bev = *(const float4*)(be + c0);
  float y[4];
  y[0] = (xv[0] - mean) * rstd * gv.x + bev.x;
  y[1] = (xv[1] - mean) * rstd * gv.y + bev.y;
  y[2] = (xv[2] - mean) * rstd * gv.z + bev.z;
  y[3] = (xv[3] - mean) * rstd * gv.w + bev.w;

  if (OF32) {
    float4 t; t.x = y[0]; t.y = y[1]; t.z = y[2]; t.w = y[3];
    *(float4*)((float*)o + base + c0) = t;
  } else {
    uint2 t;
    t.x = (unsigned)f2b(y[0]) | ((unsigned)f2b(y[1]) << 16);
    t.y = (unsigned)f2b(y[2]) | ((unsigned)f2b(y[3]) << 16);
    *(uint2*)((unsigned short*)o + base + c0) = t;
  }
}

// ---------------------------------------------------------------------------
extern "C" void kernel_launch(void* const* d_in, const int* in_sizes, int n_in,
                              void* d_out, int out_size, void* d_ws, size_t ws_size,
                              hipStream_t stream)
{
  (void)in_sizes; (void)n_in; (void)out_size; (void)ws_size;
  const float* src   = (const float*)d_in[0];
  const float* w_in  = (const float*)d_in[1];
  const float* b_in  = (const float*)d_in[2];
  const float* w_out = (const float*)d_in[3];
  const float* b_out = (const float*)d_in[4];
  const float* w1    = (const float*)d_in[5];
  const float* b1    = (const float*)d_in[6];
  const float* w2    = (const float*)d_in[7];
  const float* b2    = (const float*)d_in[8];
  const float* g1    = (const float*)d_in[9];
  const float* be1   = (const float*)d_in[10];
  const float* g2    = (const float*)d_in[11];
  const float* be2   = (const float*)d_in[12];

  char* ws = (char*)d_ws;
  unsigned short* srcb  = (unsigned short*)(ws);                 // [0, 8388608)
  unsigned short* x1b   = srcb;                                  // in-place over srcb
  unsigned short* qkv   = (unsigned short*)(ws + 8388608);       // [8388608, 33554432)
  unsigned short* ctx   = (unsigned short*)(ws + 33554432);      // [33554432, 41943040)
  unsigned short* attnb = (unsigned short*)(ws + 8388608);       // reuse qkv head
  unsigned short* ff1   = (unsigned short*)(ws + 8388608);       // [8388608, 41943040)
  unsigned short* wslot = (unsigned short*)(ws + 41943040);      // [41943040, 50331648)
  float*          outf  = (float*)d_out;
  unsigned short* w2b   = (unsigned short*)d_out;                // bf16 scratch [0, 8.4M)
  unsigned short* w1b   = (unsigned short*)((char*)d_out + 8388608); // bf16 scratch [8.4M, 16.7M)

  // 0) fused convert ALL: src->srcb; w_in|w_out->wslot; w1->w1b; w2->w2b
  conv4_k<<<dim3(8192), 256, 0, stream>>>(src, srcb, w_in, w_out, wslot, w1, w1b, w2, w2b);
  // 1) QKV projection (gemm256 8-phase, grid 192) -> bf16 qkv
  gemm256<0, 0><<<dim3(12, 16), 512, 0, stream>>>(srcb, wslot, b_in, qkv, 4096, 3072, 1024);
  // 2) banded MFMA flash attention (R21 staging) -> bf16 ctx
  attn_mfma<<<dim3(1024), 256, 0, stream>>>(qkv, ctx);
  // 3) output projection (gemm64 R19-exact) -> bf16 attnb
  gemm64<0><<<dim3(8, 64), 256, 0, stream>>>(ctx, wslot + 3145728, b_out, attnb, 4096, 1024, 1024);
  // 4) LN1(srcb bf16 + attnb bf16) -> bf16 x1b (in-place over srcb)
  ln_k<0, 0, 0><<<dim3(4096), 256, 0, stream>>>(srcb, attnb, g1, be1, x1b);
  // 5) FF1 + ReLU (gemm256 8-phase, grid 256): W from w1b (d_out scratch) -> bf16 ff1
  gemm256<1, 0><<<dim3(16, 16), 512, 0, stream>>>(x1b, w1b, b1, ff1, 4096, 4096, 1024);
  // 6) FF2 (gemm64 R19-exact): A=ff1, W=w2b (d_out scratch), out -> bf16 wslot
  gemm64<0><<<dim3(8, 64), 256, 0, stream>>>(ff1, w2b, b2, wslot, 4096, 1024, 4096);
  // 7) LN2(x1b bf16 + wslot bf16) -> f32 d_out (both scratch halves consumed)
  ln_k<0, 0, 1><<<dim3(4096), 256, 0, stream>>>(x1b, wslot, g2, be2, outf);
}